// Round 1
// 692.016 us; speedup vs baseline: 1.2001x; 1.2001x over previous
//
#include <hip/hip_runtime.h>

#define T_DIM 2048
#define H_DIM 16
#define D_DIM 128
#define TC 32      // timesteps staged per chunk
#define NCG 4      // column groups per (b,h) pair
#define CPB 32     // columns per block

typedef float v2f __attribute__((ext_vector_type(2)));

__device__ __forceinline__ unsigned f2bf(float x){   // fp32 -> bf16 (RNE), finite inputs
  unsigned u = __float_as_uint(x);
  return (u + 0x7fffu + ((u >> 16) & 1u)) >> 16;
}
__device__ __forceinline__ uint2 pack4(float4 v){
  uint2 r;
  r.x = f2bf(v.x) | (f2bf(v.y) << 16);
  r.y = f2bf(v.z) | (f2bf(v.w) << 16);
  return r;
}
// bf16 pair (rows 2j, 2j+1) -> float2
__device__ __forceinline__ v2f up2(unsigned u){
  v2f r; r.x = __uint_as_float(u << 16); r.y = __uint_as_float(u & 0xffff0000u); return r;
}
#if defined(__has_builtin) && __has_builtin(__builtin_elementwise_fma)
__device__ __forceinline__ v2f v2fma(v2f a, v2f b, v2f c){ return __builtin_elementwise_fma(a, b, c); }
#else
__device__ __forceinline__ v2f v2fma(v2f a, v2f b, v2f c){ v2f r; r.x=fmaf(a.x,b.x,c.x); r.y=fmaf(a.y,b.y,c.y); return r; }
#endif
#if defined(__has_builtin) && __has_builtin(__builtin_elementwise_max)
__device__ __forceinline__ v2f v2max(v2f a, v2f b){ return __builtin_elementwise_max(a, b); }
#else
__device__ __forceinline__ v2f v2max(v2f a, v2f b){ v2f r; r.x=fmaxf(a.x,b.x); r.y=fmaxf(a.y,b.y); return r; }
#endif
// all-reduce sum across each 16-lane DPP row via row_ror rotations
__device__ __forceinline__ float row_sum16(float x){
  x += __int_as_float(__builtin_amdgcn_update_dpp(0, __float_as_int(x), 0x121, 0xf, 0xf, true));
  x += __int_as_float(__builtin_amdgcn_update_dpp(0, __float_as_int(x), 0x122, 0xf, 0xf, true));
  x += __int_as_float(__builtin_amdgcn_update_dpp(0, __float_as_int(x), 0x124, 0xf, 0xf, true));
  x += __int_as_float(__builtin_amdgcn_update_dpp(0, __float_as_int(x), 0x128, 0xf, 0xf, true));
  return x;
}

// grid = 64 pairs * 4 colgroups = 256 blocks; block = 512 threads (8 waves/CU = 2/SIMD)
// thread: rc = tid&31 owns 4 rows (2 row-pairs), cc = tid>>5 owns 2 cols -> 8 M elems
// M held as float2 row-pairs so the update runs on v_pk_fma_f32 / v_pk_mul_f32
__global__ __launch_bounds__(512, 2)
void deltanet_kernel(const float* __restrict__ qg,
                     const float* __restrict__ kg,
                     const float* __restrict__ vg,
                     const float* __restrict__ fg,
                     const float* __restrict__ gg,
                     float* __restrict__ out)
{
  __shared__ unsigned short qs[TC][D_DIM];            // q rows, bf16
  __shared__ __align__(16) float fs [TC][D_DIM];      // f rows, fp32
  __shared__ __align__(16) float kgs[TC][D_DIM];      // k*g rows, fp32
  __shared__ __align__(16) float cols[TC][2*CPB];     // {f_c, v_c*g_c} interleaved, fp32
  __shared__ float obuf[2][TC][CPB];                  // two 16-row-half partials

  const int tid  = threadIdx.x;
  const int blk  = blockIdx.x;
  const int pair = blk >> 2;        // 0..63 = b*16 + h
  const int cg   = blk & 3;
  const int bb   = pair >> 4;
  const int hh   = pair & 15;
  const int rc   = tid & 31;        // 0..31 -> 4 rows each
  const int cc   = tid >> 5;        // 0..15 -> 2 cols each
  const int r0   = rc * 4;
  const int lc0  = cc * 2;

  const size_t base0 = ((size_t)bb * T_DIM * H_DIM + hh) * (size_t)D_DIM;
  const float* qp = qg + base0;
  const float* kp = kg + base0;
  const float* vp = vg + base0;
  const float* fp = fg + base0;
  const float* gp = gg + base0;
  float*       op = out + base0;

  v2f M0[2], M1[2];                 // [row-pair] x {col0, col1}
  #pragma unroll
  for (int j = 0; j < 2; ++j) { M0[j] = (v2f){0.f,0.f}; M1[j] = (v2f){0.f,0.f}; }

  // staging geometry: 2 iterations of 512 threads * float4 cover 32x128
  const int fl0 = tid * 4;
  const int s0g = fl0 >> 7, r0g = fl0 & 127;
  const int fl1 = (512 + tid) * 4;
  const int s1g = fl1 >> 7, r1g = fl1 & 127;
  const bool cv0 = ((r0g >> 5) == cg);   // this lane's dims fall in our column group
  const bool cv1 = ((r1g >> 5) == cg);

  float4 rq[2], rf[2], rk[2], rg[2], rv[2];

  // prologue: global loads for chunk 0 (T14 async-stage: loads live in regs)
  {
    const size_t go0 = (size_t)s0g * (H_DIM * D_DIM) + r0g;
    const size_t go1 = (size_t)s1g * (H_DIM * D_DIM) + r1g;
    rq[0] = *(const float4*)(qp + go0); rq[1] = *(const float4*)(qp + go1);
    rf[0] = *(const float4*)(fp + go0); rf[1] = *(const float4*)(fp + go1);
    rk[0] = *(const float4*)(kp + go0); rk[1] = *(const float4*)(kp + go1);
    rg[0] = *(const float4*)(gp + go0); rg[1] = *(const float4*)(gp + go1);
    if (cv0) rv[0] = *(const float4*)(vp + go0);
    if (cv1) rv[1] = *(const float4*)(vp + go1);
  }

  for (int t0 = 0; t0 < T_DIM; t0 += TC) {
    // ---------------- write staged regs -> LDS ----------------
    #pragma unroll
    for (int it = 0; it < 2; ++it) {
      const int s = it ? s1g : s0g;
      const int r = it ? r1g : r0g;
      const float4 q4 = rq[it], f4 = rf[it], k4 = rk[it], g4 = rg[it];
      *(uint2*)&qs[s][r]   = pack4(q4);
      *(float4*)&fs[s][r]  = f4;
      *(float4*)&kgs[s][r] = (float4){k4.x*g4.x, k4.y*g4.y, k4.z*g4.z, k4.w*g4.w};
      if (it ? cv1 : cv0) {
        const float4 v4 = rv[it];
        const int c2 = (r & 31) * 2;
        *(float4*)&cols[s][c2]     = (float4){f4.x, v4.x*g4.x, f4.y, v4.y*g4.y};
        *(float4*)&cols[s][c2 + 4] = (float4){f4.z, v4.z*g4.z, f4.w, v4.w*g4.w};
      }
    }
    __syncthreads();

    // ---------------- issue next chunk's global loads (latency hides under compute) ----
    if (t0 + TC < T_DIM) {
      const size_t go0 = (size_t)(t0 + TC + s0g) * (H_DIM * D_DIM) + r0g;
      const size_t go1 = (size_t)(t0 + TC + s1g) * (H_DIM * D_DIM) + r1g;
      rq[0] = *(const float4*)(qp + go0); rq[1] = *(const float4*)(qp + go1);
      rf[0] = *(const float4*)(fp + go0); rf[1] = *(const float4*)(fp + go1);
      rk[0] = *(const float4*)(kp + go0); rk[1] = *(const float4*)(kp + go1);
      rg[0] = *(const float4*)(gp + go0); rg[1] = *(const float4*)(gp + go1);
      if (cv0) rv[0] = *(const float4*)(vp + go0);
      if (cv1) rv[1] = *(const float4*)(vp + go1);
    }

    // ---------------- recurrence over the chunk (software-pipelined) ----------
    uint2  q2  = *(const uint2*)&qs[0][r0];
    float4 f4r = *(const float4*)&fs[0][r0];
    float4 k4r = *(const float4*)&kgs[0][r0];
    float4 cbv = *(const float4*)&cols[0][2*lc0];

    #pragma unroll 4
    for (int s = 0; s < TC; ++s) {
      const uint2  q2c = q2;
      const float4 f4c = f4r, k4c = k4r, cbc = cbv;
      if (s + 1 < TC) {                       // prefetch next step
        q2  = *(const uint2*)&qs[s+1][r0];
        f4r = *(const float4*)&fs[s+1][r0];
        k4r = *(const float4*)&kgs[s+1][r0];
        cbv = *(const float4*)&cols[s+1][2*lc0];
      }
      const v2f fcv0 = (v2f){cbc.x, cbc.x};
      const v2f vcv0 = (v2f){cbc.y, cbc.y};
      const v2f fcv1 = (v2f){cbc.z, cbc.z};
      const v2f vcv1 = (v2f){cbc.w, cbc.w};
      const v2f c08  = (v2f){0.8f, 0.8f};
      v2f po0 = (v2f){0.f,0.f}, po1 = (v2f){0.f,0.f};
      {   // row-pair 0
        const v2f fr = (v2f){f4c.x, f4c.y};
        const v2f kr = (v2f){k4c.x, k4c.y};
        const v2f qr = up2(q2c.x);
        M0[0] = v2fma(M0[0], v2max(fr * fcv0, c08), kr * vcv0);  // clip == max (f in [0,1])
        M1[0] = v2fma(M1[0], v2max(fr * fcv1, c08), kr * vcv1);
        po0 = v2fma(qr, M0[0], po0);
        po1 = v2fma(qr, M1[0], po1);
      }
      {   // row-pair 1
        const v2f fr = (v2f){f4c.z, f4c.w};
        const v2f kr = (v2f){k4c.z, k4c.w};
        const v2f qr = up2(q2c.y);
        M0[1] = v2fma(M0[1], v2max(fr * fcv0, c08), kr * vcv0);
        M1[1] = v2fma(M1[1], v2max(fr * fcv1, c08), kr * vcv1);
        po0 = v2fma(qr, M0[1], po0);
        po1 = v2fma(qr, M1[1], po1);
      }
      float p0 = po0.x + po0.y;
      float p1 = po1.x + po1.y;
      p0 = row_sum16(p0);                     // sum within 16-lane row groups
      p1 = row_sum16(p1);
      if ((rc & 15) == 0) {                   // lanes 0 & 16 hold the two half-sums
        *(v2f*)&obuf[rc >> 4][s][lc0] = (v2f){p0, p1};
      }
    }
    __syncthreads();

    // ---------------- flush chunk outputs (sum halves, fp32) ----------------
    {
      const int flat = tid * 2;
      const int s = flat >> 5;           // 0..31
      const int c = flat & 31;           // even
      const v2f a = *(const v2f*)&obuf[0][s][c];
      const v2f b = *(const v2f*)&obuf[1][s][c];
      const v2f o = a + b;
      *(v2f*)(op + (size_t)(t0 + s) * (H_DIM * D_DIM) + cg * CPB + c) = o;
    }
    // barrier-safety: flush(i) reads obuf before B1(i+1); compute(i+1) writes obuf
    // only after B1(i+1). Staging(i+1) LDS writes happen before B1(i+1) and only
    // after B2(i) proved compute(i) is done reading qs/fs/kgs/cols. The next-chunk
    // global loads are consumed (vmcnt-waited) only at the staging writes.
  }
}

extern "C" void kernel_launch(void* const* d_in, const int* in_sizes, int n_in,
                              void* d_out, int out_size, void* d_ws, size_t ws_size,
                              hipStream_t stream) {
  const float* q = (const float*)d_in[0];
  const float* k = (const float*)d_in[1];
  const float* v = (const float*)d_in[2];
  const float* f = (const float*)d_in[3];
  const float* g = (const float*)d_in[4];
  float* out = (float*)d_out;
  deltanet_kernel<<<dim3(64 * NCG), dim3(512), 0, stream>>>(q, k, v, f, g, out);
}